// Round 9
// baseline (98.838 us; speedup 1.0000x reference)
//
#include <hip/hip_runtime.h>
#include <math.h>

// Problem constants: B=64, L=256, H=64
#define PB 64
#define PL 256
#define PH 64
#define TEMP 0.07f
#define NEG_INF_F (-1e9f)

// Fragment-major layout: per slab (one b or one c), 16 tiles x 1024 elems.
// Tile t, half h (k 0..31 / 32..63), lane l=(g*16+n): elems
//   [t*1024 + h*512 + l*8 .. +8) = X[row = t*16 + n][k = h*32 + g*8 + j]
// -> every 64-lane fragment load is one fully-coalesced 1KB dwordx4 read.
#define KFTILE 1024
#define KFSLAB (16 * KFTILE)   // 16384 elems = 32 KB per slab
#define BGRP   8               // b's per block in the scores kernel (2 per wave)

typedef short short8 __attribute__((ext_vector_type(8)));   // 8 bf16 bit-patterns
typedef float f32x4 __attribute__((ext_vector_type(4)));

__device__ __forceinline__ unsigned short f32_to_bf16(float f) {
    unsigned int u = __float_as_uint(f);
    u += 0x7FFFu + ((u >> 16) & 1u);    // round to nearest even
    return (unsigned short)(u >> 16);
}

// fragment-major element offset for (row p, 16B-chunk cc) ; cc covers k=cc*4..cc*4+3
__device__ __forceinline__ int frag_off(int p, int cc) {
    return ((p >> 4) * KFTILE) + ((cc >> 3) * 512) +
           (((((cc >> 1) & 3) * 16) + (p & 15)) * 8) + ((cc & 1) * 4);
}

// ---------------- prep: K AND Q compact/convert into fragment-major ----------------
// blocks 0..255   : K compaction. c = bid>>2, quarter = bid&3. Tail zero rows to x16.
// blocks 256..511 : Q compaction. b = (bid-256)>>2. ALL rows >= nvQ zero-filled.
__global__ __launch_bounds__(256)
void prep_kernel(const float* __restrict__ Q,
                 const float* __restrict__ K,
                 const int*   __restrict__ kmask,
                 const int*   __restrict__ qmask,
                 unsigned short* __restrict__ Qfrag,
                 unsigned short* __restrict__ Kfrag,
                 int* __restrict__ nvK,
                 int* __restrict__ nvQ) {
    const int tid  = threadIdx.x;
    const int lane = tid & 63;
    const int wave = tid >> 6;
    __shared__ int posArr[PL];
    __shared__ int wcnt[4];

    const bool isQ = (blockIdx.x >= 256);
    const int  bid = isQ ? (blockIdx.x - 256) : blockIdx.x;
    const int  idx     = bid >> 2;     // c or b
    const int  quarter = bid & 3;

    const int* mask = isQ ? (qmask + idx * PL) : (kmask + idx * PL);
    const int km = mask[tid];
    unsigned long long bal = __ballot(km != 0);
    int within = __popcll(bal & ((1ull << lane) - 1ull));
    if (lane == 0) wcnt[wave] = __popcll(bal);
    __syncthreads();
    int base = 0;
    #pragma unroll
    for (int w = 0; w < 4; ++w) base += (w < wave) ? wcnt[w] : 0;
    posArr[tid] = km ? (base + within) : -1;
    const int nv = wcnt[0] + wcnt[1] + wcnt[2] + wcnt[3];
    __syncthreads();

    const int sub = lane >> 4;     // row-within-group 0..3
    const int cl  = lane & 15;     // 16B column chunk (k = cl*4..cl*4+3)
    const float* src = (isQ ? Q : K) + (size_t)idx * PL * PH;
    unsigned short* slab = (isQ ? Qfrag : Kfrag) + (size_t)idx * KFSLAB;

    // copy 64 rows: 4 waves x 4 rows/iter x 4 iters; 16 lanes per row (coalesced reads)
    #pragma unroll
    for (int it = 0; it < 4; ++it) {
        int r = quarter * 64 + it * 16 + wave * 4 + sub;
        int p = posArr[r];
        if (p >= 0) {
            float4 v = *(const float4*)(src + (size_t)r * PH + cl * 4);
            ushort4 o;
            o.x = f32_to_bf16(v.x); o.y = f32_to_bf16(v.y);
            o.z = f32_to_bf16(v.z); o.w = f32_to_bf16(v.w);
            *(ushort4*)(slab + frag_off(p, cl)) = o;
        }
    }

    if (!isQ) {
        // zero tail pad rows up to multiple of 16 (<=240 chunks, single shot)
        const int rows16 = (nv + 15) & ~15;
        const int padChunks = (rows16 - nv) * 16;
        if (tid < padChunks) {
            int row = nv + (tid >> 4);
            if (row >= quarter * 64 && row < quarter * 64 + 64)
                *(ushort4*)(slab + frag_off(row, tid & 15)) = (ushort4){0, 0, 0, 0};
        }
        if (quarter == 0 && tid == 0) nvK[idx] = nv;
    } else {
        // zero-fill ALL rows >= nv inside this quarter's window (1024 chunks / 4 iters)
        #pragma unroll
        for (int it = 0; it < 4; ++it) {
            int id2 = it * 256 + tid;            // (row-in-quarter, chunk)
            int row = quarter * 64 + (id2 >> 4);
            if (row >= nv)
                *(ushort4*)(slab + frag_off(row, id2 & 15)) = (ushort4){0, 0, 0, 0};
        }
        if (quarter == 0 && tid == 0) nvQ[idx] = nv;
    }
}

// ---------------- main scores kernel: one block per (c, b-group of 8) ----------------
// Deep per-wave streams: each wave preloads its lane-slice of the ENTIRE compacted
// K_c into registers (guarded compile-time unroll, <=128 VGPR), then processes 2
// whole b's (~8 (b,qp) iterations) against in-register K. No LDS, no barriers;
// only 4 Q-fragment loads per iteration, pipelined under the previous iteration's
// MFMAs. Grid 64x8 = 512 blocks, all resident.
__global__ __launch_bounds__(256, 2)
void colbert_scores_mfma(const unsigned short* __restrict__ Qfrag,
                         const unsigned short* __restrict__ Kfrag,
                         const int*   __restrict__ nvK,
                         const int*   __restrict__ nvQ,
                         float*       __restrict__ scores) {
    const int c  = blockIdx.x;
    const int bg = blockIdx.y;
    const int tid  = threadIdx.x;
    const int wave = tid >> 6;
    const int lane = tid & 63;
    const int n    = lane & 15;        // col / row-within-tile index

    const int nv   = nvK[c];
    const int nt16 = (nv + 15) >> 4;   // # K tiles (1..16), uniform per block

    // Preload lane-slice of all K tiles into registers (static indices after unroll).
    const unsigned short* kb = Kfrag + (size_t)c * KFSLAB + lane * 8;
    short8 kreg[16][2];
    #pragma unroll
    for (int ct = 0; ct < 16; ++ct) {
        if (ct < nt16) {
            kreg[ct][0] = *(const short8*)(kb + ct * KFTILE);
            kreg[ct][1] = *(const short8*)(kb + ct * KFTILE + 512);
        }
    }

    const f32x4 ZERO4 = (f32x4){0.f, 0.f, 0.f, 0.f};

    #pragma unroll 1
    for (int bo = 0; bo < 2; ++bo) {
        const int b  = bg * BGRP + wave * 2 + bo;
        const int nq = nvQ[b];
        const int nQP = (nq + 31) >> 5;          // q-tile-pairs for this b
        const unsigned short* qslab = Qfrag + (size_t)b * KFSLAB + lane * 8;

        float partial = 0.0f;

        #pragma unroll 1
        for (int qp = 0; qp < nQP; ++qp) {
            const unsigned short* qbase = qslab + qp * 2 * KFTILE;
            short8 a00 = *(const short8*)(qbase);
            short8 a01 = *(const short8*)(qbase + 512);
            short8 a10 = *(const short8*)(qbase + 1024);
            short8 a11 = *(const short8*)(qbase + 1536);

            float maxv[2][4];
            #pragma unroll
            for (int t = 0; t < 2; ++t)
                #pragma unroll
                for (int r = 0; r < 4; ++r) maxv[t][r] = NEG_INF_F;

            #pragma unroll
            for (int ct = 0; ct < 16; ++ct) {
                if (ct < nt16) {
                    // per-tile column-validity bias (all-zero except last tile)
                    const float bv = (ct * 16 + n < nv) ? 0.0f : NEG_INF_F;
                    const f32x4 B4 = (f32x4){bv, bv, bv, bv};

                    f32x4 acc0 = __builtin_amdgcn_mfma_f32_16x16x32_bf16(a00, kreg[ct][0], B4, 0, 0, 0);
                    acc0 = __builtin_amdgcn_mfma_f32_16x16x32_bf16(a01, kreg[ct][1], acc0, 0, 0, 0);
                    f32x4 acc1 = __builtin_amdgcn_mfma_f32_16x16x32_bf16(a10, kreg[ct][0], B4, 0, 0, 0);
                    acc1 = __builtin_amdgcn_mfma_f32_16x16x32_bf16(a11, kreg[ct][1], acc1, 0, 0, 0);

                    #pragma unroll
                    for (int r = 0; r < 4; ++r) {
                        maxv[0][r] = fmaxf(maxv[0][r], acc0[r]);
                        maxv[1][r] = fmaxf(maxv[1][r], acc1[r]);
                    }
                }
            }

            // col-reduce over the 16 lanes of each quad group; accumulate row sums
            #pragma unroll
            for (int t = 0; t < 2; ++t)
                #pragma unroll
                for (int r = 0; r < 4; ++r) {
                    float mv = maxv[t][r];
                    mv = fmaxf(mv, __shfl_xor(mv, 1, 16));
                    mv = fmaxf(mv, __shfl_xor(mv, 2, 16));
                    mv = fmaxf(mv, __shfl_xor(mv, 4, 16));
                    mv = fmaxf(mv, __shfl_xor(mv, 8, 16));
                    if (n == 0) partial += mv;   // each (g,t,r) = one distinct q row
                }
        }

        // sum partials across the 4 n==0 lanes (0,16,32,48); lane 0 stores
        partial += __shfl_xor(partial, 16, 64);
        partial += __shfl_xor(partial, 32, 64);
        if (lane == 0) scores[b * PB + c] = partial * (1.0f / TEMP);
    }
}

// ---------------- finalize: log-softmax CE ----------------
__global__ void finalize_kernel(const float* __restrict__ scores,
                                const int*   __restrict__ labels,
                                float*       __restrict__ out) {
    const int r = threadIdx.x;   // 64 threads, one per row
    const float* row = scores + r * PB;
    float mx = NEG_INF_F;
    for (int j = 0; j < PB; ++j) mx = fmaxf(mx, row[j]);
    float se = 0.0f;
    for (int j = 0; j < PB; ++j) se += expf(row[j] - mx);
    float logp_diag = row[r] - mx - logf(se);
    float w = (float)labels[r];
    float wd = w * logp_diag;
    #pragma unroll
    for (int off = 32; off >= 1; off >>= 1) {
        wd += __shfl_xor(wd, off, 64);
        w  += __shfl_xor(w,  off, 64);
    }
    if (r == 0) out[0] = -wd / fmaxf(w, 1.0f);
}

extern "C" void kernel_launch(void* const* d_in, const int* in_sizes, int n_in,
                              void* d_out, int out_size, void* d_ws, size_t ws_size,
                              hipStream_t stream) {
    const float* Q      = (const float*)d_in[0];
    const float* K      = (const float*)d_in[1];
    const int*   labels = (const int*)d_in[2];
    const int*   qmask  = (const int*)d_in[3];
    const int*   kmask  = (const int*)d_in[4];
    float*       out    = (float*)d_out;

    // ws layout: [scores 16KB][Qfrag 2MB][Kfrag 2MB][nvK 256B][nvQ 256B]
    char* ws = (char*)d_ws;
    float*          scores = (float*)ws;
    unsigned short* Qfrag  = (unsigned short*)(ws + 16 * 1024);
    unsigned short* Kfrag  = (unsigned short*)(ws + 16 * 1024 + 2 * 1024 * 1024);
    int*            nvK    = (int*)(ws + 16 * 1024 + 4 * 1024 * 1024);
    int*            nvQ    = nvK + 64;

    prep_kernel<<<512, 256, 0, stream>>>(Q, K, kmask, qmask, Qfrag, Kfrag, nvK, nvQ);

    dim3 grid(PB, PB / BGRP);
    colbert_scores_mfma<<<grid, 256, 0, stream>>>(Qfrag, Kfrag, nvK, nvQ, scores);
    finalize_kernel<<<1, 64, 0, stream>>>(scores, labels, out);
}